// Round 17
// baseline (150.972 us; speedup 1.0000x reference)
//
#include <hip/hip_runtime.h>
#include <hip/hip_bf16.h>
#include <math.h>

using bf16 = __hip_bfloat16;
typedef __attribute__((ext_vector_type(8))) short bf16x8;
typedef __attribute__((ext_vector_type(4))) float f32x4;
typedef __attribute__((ext_vector_type(4))) unsigned short us4;

#define GAS __attribute__((address_space(1)))
#define LAS __attribute__((address_space(3)))

__device__ __forceinline__ void gload_lds16(const bf16* g, bf16* lds) {
  __builtin_amdgcn_global_load_lds((const GAS void*)g, (LAS void*)lds, 16, 0, 0);
}
__device__ __forceinline__ float b2f(unsigned short u) {
  union { unsigned short s; bf16 b; } x; x.s = u; return __bfloat162float(x.b);
}

// ---------------- compaction (atomic-free, stable => deterministic) ----------------
__global__ __launch_bounds__(256) void hist_k(const int* __restrict__ lab,
                                              int* __restrict__ blockHist) {
  const int blk = blockIdx.x, t = threadIdx.x;
  const int lane = t & 63, w = t >> 6;
  const int d = lab[blk * 256 + t];
  __shared__ int wc[4][3];
#pragma unroll
  for (int dd = 0; dd < 3; ++dd) {
    unsigned long long m = __ballot(d == dd);
    if (lane == 0) wc[w][dd] = __popcll(m);
  }
  __syncthreads();
  if (t < 3) blockHist[blk * 3 + t] = wc[0][t] + wc[1][t] + wc[2][t] + wc[3][t];
}

// scatter with INLINE scan: each block redundantly scans the 64x3 histogram in LDS;
// block 0 writes meta. Stable rank => deterministic perm/iperm.
__global__ __launch_bounds__(256) void scatter2_k(const int* __restrict__ lab,
                                                  const int* __restrict__ blockHist,
                                                  int* __restrict__ meta,
                                                  int* __restrict__ perm,
                                                  int* __restrict__ iperm) {
  const int blk = blockIdx.x, t = threadIdx.x;
  const int lane = t & 63, w = t >> 6;
  __shared__ int h[64][3];
  __shared__ int tot[3], pres[3];
  __shared__ int wc[4][3];
  if (t < 192) h[t / 3][t % 3] = blockHist[t];
  __syncthreads();
  if (t < 3) {
    int pre = 0, s = 0;
    for (int b = 0; b < 64; ++b) {
      if (b == blk) pre = s;
      s += h[b][t];
    }
    tot[t] = s;
    pres[t] = pre;
  }
  __syncthreads();
  if (blk == 0 && t == 0) {
    meta[0] = tot[0]; meta[1] = tot[1]; meta[2] = tot[2];
    meta[4] = 0; meta[5] = tot[0]; meta[6] = tot[0] + tot[1];
  }
  const int i = blk * 256 + t;
  const int d = lab[i];
  unsigned long long mymask = 0;
#pragma unroll
  for (int dd = 0; dd < 3; ++dd) {
    unsigned long long m = __ballot(d == dd);
    if (lane == 0) wc[w][dd] = __popcll(m);
    if (dd == d) mymask = m;
  }
  __syncthreads();
  int woff = 0;
  for (int ww = 0; ww < w; ++ww) woff += wc[ww][d];
  const int dbase = (d == 0) ? 0 : (d == 1 ? tot[0] : tot[0] + tot[1]);
  const unsigned long long lt = ((unsigned long long)1 << lane) - 1;
  const int rank = dbase + pres[d] + woff + __popcll(mymask & lt);
  perm[rank] = i;
  iperm[i] = rank;
}

// ------- merged prep: blocks 0..383 = LDS-tiled W1/W2 transpose+cvt; rest = cvt -------
__global__ __launch_bounds__(256) void prep_k(const float* __restrict__ x,
                                              const float* __restrict__ txt,
                                              const float* __restrict__ W1,
                                              const float* __restrict__ W2,
                                              const int* __restrict__ iperm,
                                              bf16* __restrict__ Xbc,
                                              bf16* __restrict__ Tb,
                                              bf16* __restrict__ W1T,
                                              bf16* __restrict__ W2T) {
  __shared__ float s[64][65];
  if (blockIdx.x < 384) {
    int b = blockIdx.x;
    const float* W; bf16* WT; int R, C;
    if (b < 192) { W = W1; WT = W1T; R = 1024; C = 256; }
    else         { b -= 192; W = W2; WT = W2T; R = 256; C = 1024; }
    const int d = b / 64, tb = b % 64;
    const int tilesPerRow = C / 64;
    const int r0 = (tb / tilesPerRow) * 64;
    const int c0 = (tb % tilesPerRow) * 64;
    const float* Wd = W + (size_t)d * R * C;
    bf16* WTd = WT + (size_t)d * R * C;
    const int tx = threadIdx.x & 63, ty = threadIdx.x >> 6;
#pragma unroll
    for (int i = 0; i < 16; ++i)
      s[ty + i * 4][tx] = Wd[(size_t)(r0 + ty + i * 4) * C + c0 + tx];
    __syncthreads();
#pragma unroll
    for (int i = 0; i < 16; ++i)
      WTd[(size_t)(c0 + ty + i * 4) * R + r0 + tx] = __float2bfloat16(s[tx][ty + i * 4]);
    return;
  }
  const int nx = 16384 * 1024 / 4;
  const int ntext = 1536 * 1024;
  const int total = nx + ntext;
  for (int i = (blockIdx.x - 384) * 256 + threadIdx.x; i < total; i += 2048 * 256) {
    if (i < nx) {
      const int row = i >> 8, c4 = i & 255;
      float4 v = ((const float4*)x)[i];
      bf16 t[4] = {__float2bfloat16(v.x), __float2bfloat16(v.y),
                   __float2bfloat16(v.z), __float2bfloat16(v.w)};
      ((us4*)Xbc)[(size_t)iperm[row] * 256 + c4] = *(const us4*)t;
    } else {
      int jj = i - nx;
      Tb[jj] = (jj < 1380 * 1024) ? __float2bfloat16(txt[jj]) : __float2bfloat16(0.f);
    }
  }
}

// -------- 128^2 2-phase GEMM for GEMM1/GEMM2 — dense compacted rows, BK templated --------
template <int EPI, int NBLK, int BK>
__global__ __launch_bounds__(256) void gemm_bt(
    const bf16* __restrict__ A, const bf16* __restrict__ BT, bf16* __restrict__ Cv,
    const int* __restrict__ meta, int N, int K, int ldc, int Nvalid,
    const bf16* __restrict__ xb, float* __restrict__ ssp) {
  const int bid = blockIdx.x;
  const int xcd = bid & 7;
  const int seq = bid >> 3;
  const int nblkidx = seq % NBLK;
  const int dm = xcd + 8 * (seq / NBLK);
  const int dom = dm >> 7;
  const int mblk = dm & 127;

  const int cnt = meta[dom];
  const int base = meta[4 + dom];
  BT += (size_t)dom * N * K;

  const int m0 = mblk * 128;
  if (m0 >= cnt) return;
  const int n0 = nblkidx * 128;

  constexpr int CH = BK / 8;
  __shared__ bf16 sA[2][128][BK];
  __shared__ bf16 sB[2][128][BK];

  const int tid = threadIdx.x;
  const int wid = tid >> 6;
  const int lane = tid & 63;
  const int fr = lane & 15;
  const int fq = lane >> 4;

  auto stage = [&](int buf, int kt) {
    const int koff = kt * BK;
#pragma unroll
    for (int L = 0; L < CH / 2; ++L) {
      const int idx = L * 256 + tid;
      const int r = idx / CH, c = idx % CH;
      int ar = m0 + r; if (ar > cnt - 1) ar = cnt - 1;
      gload_lds16(A + (size_t)(base + ar) * K + koff + ((c ^ (r & (CH - 1))) << 3),
                  &sA[buf][0][0] + ((idx & ~63) << 3));
    }
#pragma unroll
    for (int L = 0; L < CH / 2; ++L) {
      const int idx = L * 256 + tid;
      const int r = idx / CH, c = idx % CH;
      gload_lds16(BT + (size_t)(n0 + r) * K + koff + ((c ^ (r & (CH - 1))) << 3),
                  &sB[buf][0][0] + ((idx & ~63) << 3));
    }
  };

  f32x4 acc[4][4];
#pragma unroll
  for (int m = 0; m < 4; ++m)
#pragma unroll
    for (int n = 0; n < 4; ++n) acc[m][n] = (f32x4){0.f, 0.f, 0.f, 0.f};

  const int nk = K / BK;
  stage(0, 0);
  __syncthreads();
  const int wr = wid >> 1, wc = wid & 1;
  for (int kt = 0; kt < nk; ++kt) {
    const int cur = kt & 1;
    if (kt + 1 < nk) stage(cur ^ 1, kt + 1);
#pragma unroll
    for (int kk = 0; kk < BK / 32; ++kk) {
      const int rchunk = (((kk << 2) + fq) ^ (fr & (CH - 1))) << 3;
      bf16x8 af[4], bfr[4];
#pragma unroll
      for (int m = 0; m < 4; ++m)
        af[m] = *(const bf16x8*)&sA[cur][wr * 64 + m * 16 + fr][0 + rchunk];
#pragma unroll
      for (int n = 0; n < 4; ++n)
        bfr[n] = *(const bf16x8*)&sB[cur][wc * 64 + n * 16 + fr][0 + rchunk];
#pragma unroll
      for (int m = 0; m < 4; ++m)
#pragma unroll
        for (int n = 0; n < 4; ++n)
          acc[m][n] = __builtin_amdgcn_mfma_f32_16x16x32_bf16(af[m], bfr[n], acc[m][n], 0, 0, 0);
    }
    __syncthreads();
  }

  if (EPI == 0) {
#pragma unroll
    for (int m = 0; m < 4; ++m) {
#pragma unroll
      for (int r = 0; r < 4; ++r) {
        const int p = m0 + wr * 64 + m * 16 + fq * 4 + r;
        if (p < cnt) {
          const size_t crow = (size_t)(base + p);
#pragma unroll
          for (int n = 0; n < 4; ++n) {
            const int col = n0 + wc * 64 + n * 16 + fr;
            if (col < Nvalid)
              Cv[crow * (size_t)ldc + col] = __float2bfloat16(fmaxf(acc[m][n][r], 0.f));
          }
        }
      }
    }
  } else {
    __shared__ float ssred[128][2];
#pragma unroll
    for (int m = 0; m < 4; ++m) {
#pragma unroll
      for (int r = 0; r < 4; ++r) {
        const int lr = wr * 64 + m * 16 + fq * 4 + r;
        const int p = m0 + lr;
        float rowss = 0.f;
        if (p < cnt) {
          const size_t crow = (size_t)(base + p);
#pragma unroll
          for (int n = 0; n < 4; ++n) {
            const int col = n0 + wc * 64 + n * 16 + fr;
            const float g = 0.2f * fmaxf(acc[m][n][r], 0.f) +
                            0.8f * b2f(*(const unsigned short*)&xb[crow * 1024 + col]);
            Cv[crow * (size_t)ldc + col] = __float2bfloat16(g);
            rowss += g * g;
          }
        }
        rowss += __shfl_xor(rowss, 1, 16);
        rowss += __shfl_xor(rowss, 2, 16);
        rowss += __shfl_xor(rowss, 4, 16);
        rowss += __shfl_xor(rowss, 8, 16);
        if (fr == 0) ssred[lr][wc] = rowss;
      }
    }
    __syncthreads();
    if (tid < 128) {
      const int p = m0 + tid;
      if (p < cnt)
        ssp[(size_t)nblkidx * 16384 + base + p] = ssred[tid][0] + ssred[tid][1];
    }
  }
}

// ====== GEMM3: counted-vmcnt + split lgkmcnt(11) read-wait (R13 winner + surgical fix) ======
// Per tile t (slot s=t&1):
//   issue kk0 reads (11 ds_read, SB-pinned) | issue kk1 reads (11) |
//   lgkmcnt(11)  <- FIFO: kk0's reads done; kk1's drain under kk0 MFMA
//   24 MFMA (kk0)
//   lgkmcnt(0) | BAR  <- every wave's slot-s reads complete
//   STAGE(t+2 -> slot s)   (proven-safe overwrite)
//   24 MFMA (kk1)
//   vmcnt(10)  <- drains exactly tile t+1 (FIFO, 10 loads/tile); never young loads
//   BAR
// Same K-order & fragment mapping => bit-identical output to R13/R16.
__global__ __launch_bounds__(256, 2) void gemm3_cnt(
    const bf16* __restrict__ A, const bf16* __restrict__ BT,
    float* __restrict__ C, const float* __restrict__ scale_ptr,
    const float* __restrict__ ssp, const int* __restrict__ perm) {
  extern __shared__ bf16 smem[];
  bf16* sA0 = smem;            // [2][128][64] = 32KB
  bf16* sB0 = smem + 16384;    // [2][192][64] = 48KB

  const int tid = threadIdx.x;
  const int lane = tid & 63, wid = tid >> 6;
  const int wr = wid >> 1, wc = wid & 1;     // 2x2; wave C = 64x96
  const int fr = lane & 15, fq = lane >> 4;

  const int bid = blockIdx.x;
  const int x = bid & 7, seq = bid >> 3;
  const int mb = x * 16 + (seq >> 3), nb = seq & 7;
  const int m0 = mb << 7, n0 = nb * 192;

  auto STAGE = [&](int t) {     // A 4 + B 6 gload/thread = 10 VMEM ops/thread/tile
    const int s = t & 1, koff = t << 6;
    bf16* da = sA0 + (s << 13);
#pragma unroll
    for (int L = 0; L < 4; ++L) {
      const int idx = (L << 8) + tid;
      const int r = idx >> 3, c = idx & 7;
      gload_lds16(A + (size_t)(m0 + r) * 1024 + koff + ((c ^ (r & 7)) << 3),
                  da + ((idx & ~63) << 3));
    }
    bf16* db = sB0 + s * 12288;
#pragma unroll
    for (int L = 0; L < 6; ++L) {
      const int idx = (L << 8) + tid;
      const int r = idx >> 3, c = idx & 7;
      gload_lds16(BT + (size_t)(n0 + r) * 1024 + koff + ((c ^ (r & 7)) << 3),
                  db + ((idx & ~63) << 3));
    }
  };
  auto LDA = [&](int s, int kk, bf16x8* dst) {
    const bf16* base = sA0 + (s << 13);
#pragma unroll
    for (int m = 0; m < 4; ++m) {
      const int row = (wr << 6) + (m << 4) + fr;
      dst[m] = *(const bf16x8*)(base + (row << 6) + ((((kk << 2) + fq) ^ (fr & 7)) << 3));
    }
  };
  auto LDB = [&](int s, int kk, bf16x8* dst) {
    const bf16* base = sB0 + s * 12288;
#pragma unroll
    for (int n = 0; n < 6; ++n) {
      const int row = wc * 96 + (n << 4) + fr;
      dst[n] = *(const bf16x8*)(base + (row << 6) + ((((kk << 2) + fq) ^ (fr & 7)) << 3));
    }
  };

  f32x4 acc[4][6];
#pragma unroll
  for (int m = 0; m < 4; ++m)
#pragma unroll
    for (int n = 0; n < 6; ++n) acc[m][n] = (f32x4){0.f, 0.f, 0.f, 0.f};

  STAGE(0); STAGE(1);
  asm volatile("s_waitcnt vmcnt(10)" ::: "memory");
  __builtin_amdgcn_s_barrier();

  const int nt = 16;
  for (int t = 0; t < nt; ++t) {
    const int s = t & 1;
    bf16x8 a0[4], a1[4], b0[6], b1[6];
    // group 1: kk0 reads (pinned before group 2)
    LDA(s, 0, a0); LDB(s, 0, b0);
    __builtin_amdgcn_sched_barrier(0);
    // group 2: kk1 reads
    LDA(s, 1, a1); LDB(s, 1, b1);
    __builtin_amdgcn_sched_barrier(0);
    // counted wait: <=11 outstanding => group 1 (kk0) complete
    asm volatile("s_waitcnt lgkmcnt(11)" ::: "memory");
    __builtin_amdgcn_sched_barrier(0);       // rule 18
    __builtin_amdgcn_s_setprio(1);
#pragma unroll
    for (int m = 0; m < 4; ++m)
#pragma unroll
      for (int n = 0; n < 6; ++n)
        acc[m][n] = __builtin_amdgcn_mfma_f32_16x16x32_bf16(a0[m], b0[n], acc[m][n], 0, 0, 0);
    __builtin_amdgcn_s_setprio(0);
    // all own reads done; barrier => every wave's slot-s reads complete
    asm volatile("s_waitcnt lgkmcnt(0)" ::: "memory");
    __builtin_amdgcn_sched_barrier(0);
    __builtin_amdgcn_s_barrier();
    __builtin_amdgcn_sched_barrier(0);
    if (t + 2 < nt) STAGE(t + 2);            // overwrite slot s (safe)
    __builtin_amdgcn_s_setprio(1);
#pragma unroll
    for (int m = 0; m < 4; ++m)
#pragma unroll
      for (int n = 0; n < 6; ++n)
        acc[m][n] = __builtin_amdgcn_mfma_f32_16x16x32_bf16(a1[m], b1[n], acc[m][n], 0, 0, 0);
    __builtin_amdgcn_s_setprio(0);
    if (t + 2 < nt) {
      asm volatile("s_waitcnt vmcnt(10)" ::: "memory");   // drain t+1, keep t+2 flying
    } else if (t + 1 < nt) {
      asm volatile("s_waitcnt vmcnt(0)" ::: "memory");
    }
    __builtin_amdgcn_sched_barrier(0);
    __builtin_amdgcn_s_barrier();
    __builtin_amdgcn_sched_barrier(0);
  }

  float* rlds = (float*)smem;
  int*   plds = (int*)((char*)smem + 512);
  if (tid < 128) {
    float s = 0.f;
#pragma unroll
    for (int b = 0; b < 8; ++b) s += ssp[b * 16384 + m0 + tid];
    rlds[tid] = rsqrtf(s);
    plds[tid] = perm[m0 + tid];
  }
  __syncthreads();

  const float sc = expf(*scale_ptr);
#pragma unroll
  for (int m = 0; m < 4; ++m) {
    const int lrow = (wr << 6) + (m << 4) + (fq << 2);
#pragma unroll
    for (int r = 0; r < 4; ++r) {
      const float rv = sc * rlds[lrow + r];
      const size_t orow = (size_t)plds[lrow + r];
#pragma unroll
      for (int n = 0; n < 6; ++n) {
        const int gcol = n0 + wc * 96 + (n << 4) + fr;
        if (gcol < 1380) C[orow * 1380 + gcol] = acc[m][n][r] * rv;
      }
    }
  }
}

extern "C" void kernel_launch(void* const* d_in, const int* in_sizes, int n_in,
                              void* d_out, int out_size, void* d_ws, size_t ws_size,
                              hipStream_t stream) {
  (void)in_sizes; (void)n_in; (void)out_size; (void)ws_size;
  const float* x    = (const float*)d_in[0];
  const int*   lab  = (const int*)d_in[1];
  const float* W1   = (const float*)d_in[2];
  const float* W2   = (const float*)d_in[3];
  const float* text = (const float*)d_in[4];
  const float* lsc  = (const float*)d_in[5];
  float* out = (float*)d_out;

  const int B = 16384, D = 1024, R = 256, NTP = 1536;

  char* p = (char*)d_ws;
  auto carve = [&](size_t bytes) {
    char* r = p;
    p += (bytes + 255) & ~(size_t)255;
    return r;
  };
  int*   meta  = (int*)carve(64);
  int*   bhist = (int*)carve(64 * 3 * 4);
  int*   perm  = (int*)carve((size_t)B * 4);
  int*   iperm = (int*)carve((size_t)B * 4);
  float* ssp   = (float*)carve((size_t)8 * B * 4);
  bf16*  Xbc   = (bf16*)carve((size_t)B * D * 2);
  bf16*  W1T   = (bf16*)carve((size_t)3 * R * D * 2);
  bf16*  W2T   = (bf16*)carve((size_t)3 * D * R * 2);
  bf16*  Tb    = (bf16*)carve((size_t)NTP * D * 2);
  bf16*  H     = (bf16*)carve((size_t)B * R * 2);
  bf16*  Fbc   = (bf16*)carve((size_t)B * D * 2);

  hist_k<<<B / 256, 256, 0, stream>>>(lab, bhist);
  scatter2_k<<<B / 256, 256, 0, stream>>>(lab, bhist, meta, perm, iperm);

  prep_k<<<384 + 2048, 256, 0, stream>>>(x, text, W1, W2, iperm, Xbc, Tb, W1T, W2T);

  // GEMM1: H = relu(Xbc @ W1T[dom]^T), BK=64 — 768 blocks
  gemm_bt<0, 2, 64><<<768, 256, 0, stream>>>(
      Xbc, W1T, H, meta, R, D, R, R, nullptr, nullptr);
  // GEMM2: Fbc = 0.2*relu(H @ W2T^T) + 0.8*Xbc, BK=64 — 3072 blocks
  gemm_bt<1, 8, 64><<<3072, 256, 0, stream>>>(
      H, W2T, Fbc, meta, D, R, D, D, Xbc, ssp);
  // GEMM3: out[perm[row]] = exp(ls) * rinv[row] * (Fbc @ Tb^T) — split-wait counted-vmcnt
  gemm3_cnt<<<1024, 256, 81920, stream>>>(Fbc, Tb, out, lsc, ssp, perm);
}

// Round 18
// 150.537 us; speedup vs baseline: 1.0029x; 1.0029x over previous
//
#include <hip/hip_runtime.h>
#include <hip/hip_bf16.h>
#include <math.h>

using bf16 = __hip_bfloat16;
typedef __attribute__((ext_vector_type(8))) short bf16x8;
typedef __attribute__((ext_vector_type(4))) float f32x4;
typedef __attribute__((ext_vector_type(4))) unsigned short us4;

#define GAS __attribute__((address_space(1)))
#define LAS __attribute__((address_space(3)))

__device__ __forceinline__ void gload_lds16(const bf16* g, bf16* lds) {
  __builtin_amdgcn_global_load_lds((const GAS void*)g, (LAS void*)lds, 16, 0, 0);
}
__device__ __forceinline__ float b2f(unsigned short u) {
  union { unsigned short s; bf16 b; } x; x.s = u; return __bfloat162float(x.b);
}

// ---------------- compaction (atomic-free, stable => deterministic) ----------------
__global__ __launch_bounds__(256) void hist_k(const int* __restrict__ lab,
                                              int* __restrict__ blockHist) {
  const int blk = blockIdx.x, t = threadIdx.x;
  const int lane = t & 63, w = t >> 6;
  const int d = lab[blk * 256 + t];
  __shared__ int wc[4][3];
#pragma unroll
  for (int dd = 0; dd < 3; ++dd) {
    unsigned long long m = __ballot(d == dd);
    if (lane == 0) wc[w][dd] = __popcll(m);
  }
  __syncthreads();
  if (t < 3) blockHist[blk * 3 + t] = wc[0][t] + wc[1][t] + wc[2][t] + wc[3][t];
}

// scatter with INLINE scan: each block redundantly scans the 64x3 histogram in LDS;
// block 0 writes meta. Stable rank => deterministic perm/iperm.
__global__ __launch_bounds__(256) void scatter2_k(const int* __restrict__ lab,
                                                  const int* __restrict__ blockHist,
                                                  int* __restrict__ meta,
                                                  int* __restrict__ perm,
                                                  int* __restrict__ iperm) {
  const int blk = blockIdx.x, t = threadIdx.x;
  const int lane = t & 63, w = t >> 6;
  __shared__ int h[64][3];
  __shared__ int tot[3], pres[3];
  __shared__ int wc[4][3];
  if (t < 192) h[t / 3][t % 3] = blockHist[t];
  __syncthreads();
  if (t < 3) {
    int pre = 0, s = 0;
    for (int b = 0; b < 64; ++b) {
      if (b == blk) pre = s;
      s += h[b][t];
    }
    tot[t] = s;
    pres[t] = pre;
  }
  __syncthreads();
  if (blk == 0 && t == 0) {
    meta[0] = tot[0]; meta[1] = tot[1]; meta[2] = tot[2];
    meta[4] = 0; meta[5] = tot[0]; meta[6] = tot[0] + tot[1];
  }
  const int i = blk * 256 + t;
  const int d = lab[i];
  unsigned long long mymask = 0;
#pragma unroll
  for (int dd = 0; dd < 3; ++dd) {
    unsigned long long m = __ballot(d == dd);
    if (lane == 0) wc[w][dd] = __popcll(m);
    if (dd == d) mymask = m;
  }
  __syncthreads();
  int woff = 0;
  for (int ww = 0; ww < w; ++ww) woff += wc[ww][d];
  const int dbase = (d == 0) ? 0 : (d == 1 ? tot[0] : tot[0] + tot[1]);
  const unsigned long long lt = ((unsigned long long)1 << lane) - 1;
  const int rank = dbase + pres[d] + woff + __popcll(mymask & lt);
  perm[rank] = i;
  iperm[i] = rank;
}

// ------- merged prep: blocks 0..383 = LDS-tiled W1/W2 transpose+cvt; rest = cvt -------
__global__ __launch_bounds__(256) void prep_k(const float* __restrict__ x,
                                              const float* __restrict__ txt,
                                              const float* __restrict__ W1,
                                              const float* __restrict__ W2,
                                              const int* __restrict__ iperm,
                                              bf16* __restrict__ Xbc,
                                              bf16* __restrict__ Tb,
                                              bf16* __restrict__ W1T,
                                              bf16* __restrict__ W2T) {
  __shared__ float s[64][65];
  if (blockIdx.x < 384) {
    int b = blockIdx.x;
    const float* W; bf16* WT; int R, C;
    if (b < 192) { W = W1; WT = W1T; R = 1024; C = 256; }
    else         { b -= 192; W = W2; WT = W2T; R = 256; C = 1024; }
    const int d = b / 64, tb = b % 64;
    const int tilesPerRow = C / 64;
    const int r0 = (tb / tilesPerRow) * 64;
    const int c0 = (tb % tilesPerRow) * 64;
    const float* Wd = W + (size_t)d * R * C;
    bf16* WTd = WT + (size_t)d * R * C;
    const int tx = threadIdx.x & 63, ty = threadIdx.x >> 6;
#pragma unroll
    for (int i = 0; i < 16; ++i)
      s[ty + i * 4][tx] = Wd[(size_t)(r0 + ty + i * 4) * C + c0 + tx];
    __syncthreads();
#pragma unroll
    for (int i = 0; i < 16; ++i)
      WTd[(size_t)(c0 + ty + i * 4) * R + r0 + tx] = __float2bfloat16(s[tx][ty + i * 4]);
    return;
  }
  const int nx = 16384 * 1024 / 4;
  const int ntext = 1536 * 1024;
  const int total = nx + ntext;
  for (int i = (blockIdx.x - 384) * 256 + threadIdx.x; i < total; i += 2048 * 256) {
    if (i < nx) {
      const int row = i >> 8, c4 = i & 255;
      float4 v = ((const float4*)x)[i];
      bf16 t[4] = {__float2bfloat16(v.x), __float2bfloat16(v.y),
                   __float2bfloat16(v.z), __float2bfloat16(v.w)};
      ((us4*)Xbc)[(size_t)iperm[row] * 256 + c4] = *(const us4*)t;
    } else {
      int jj = i - nx;
      Tb[jj] = (jj < 1380 * 1024) ? __float2bfloat16(txt[jj]) : __float2bfloat16(0.f);
    }
  }
}

// -------- 128^2 2-phase GEMM for GEMM1/GEMM2 — dense compacted rows, BK templated --------
template <int EPI, int NBLK, int BK>
__global__ __launch_bounds__(256) void gemm_bt(
    const bf16* __restrict__ A, const bf16* __restrict__ BT, bf16* __restrict__ Cv,
    const int* __restrict__ meta, int N, int K, int ldc, int Nvalid,
    const bf16* __restrict__ xb, float* __restrict__ ssp) {
  const int bid = blockIdx.x;
  const int xcd = bid & 7;
  const int seq = bid >> 3;
  const int nblkidx = seq % NBLK;
  const int dm = xcd + 8 * (seq / NBLK);
  const int dom = dm >> 7;
  const int mblk = dm & 127;

  const int cnt = meta[dom];
  const int base = meta[4 + dom];
  BT += (size_t)dom * N * K;

  const int m0 = mblk * 128;
  if (m0 >= cnt) return;
  const int n0 = nblkidx * 128;

  constexpr int CH = BK / 8;
  __shared__ bf16 sA[2][128][BK];
  __shared__ bf16 sB[2][128][BK];

  const int tid = threadIdx.x;
  const int wid = tid >> 6;
  const int lane = tid & 63;
  const int fr = lane & 15;
  const int fq = lane >> 4;

  auto stage = [&](int buf, int kt) {
    const int koff = kt * BK;
#pragma unroll
    for (int L = 0; L < CH / 2; ++L) {
      const int idx = L * 256 + tid;
      const int r = idx / CH, c = idx % CH;
      int ar = m0 + r; if (ar > cnt - 1) ar = cnt - 1;
      gload_lds16(A + (size_t)(base + ar) * K + koff + ((c ^ (r & (CH - 1))) << 3),
                  &sA[buf][0][0] + ((idx & ~63) << 3));
    }
#pragma unroll
    for (int L = 0; L < CH / 2; ++L) {
      const int idx = L * 256 + tid;
      const int r = idx / CH, c = idx % CH;
      gload_lds16(BT + (size_t)(n0 + r) * K + koff + ((c ^ (r & (CH - 1))) << 3),
                  &sB[buf][0][0] + ((idx & ~63) << 3));
    }
  };

  f32x4 acc[4][4];
#pragma unroll
  for (int m = 0; m < 4; ++m)
#pragma unroll
    for (int n = 0; n < 4; ++n) acc[m][n] = (f32x4){0.f, 0.f, 0.f, 0.f};

  const int nk = K / BK;
  stage(0, 0);
  __syncthreads();
  const int wr = wid >> 1, wc = wid & 1;
  for (int kt = 0; kt < nk; ++kt) {
    const int cur = kt & 1;
    if (kt + 1 < nk) stage(cur ^ 1, kt + 1);
#pragma unroll
    for (int kk = 0; kk < BK / 32; ++kk) {
      const int rchunk = (((kk << 2) + fq) ^ (fr & (CH - 1))) << 3;
      bf16x8 af[4], bfr[4];
#pragma unroll
      for (int m = 0; m < 4; ++m)
        af[m] = *(const bf16x8*)&sA[cur][wr * 64 + m * 16 + fr][0 + rchunk];
#pragma unroll
      for (int n = 0; n < 4; ++n)
        bfr[n] = *(const bf16x8*)&sB[cur][wc * 64 + n * 16 + fr][0 + rchunk];
#pragma unroll
      for (int m = 0; m < 4; ++m)
#pragma unroll
        for (int n = 0; n < 4; ++n)
          acc[m][n] = __builtin_amdgcn_mfma_f32_16x16x32_bf16(af[m], bfr[n], acc[m][n], 0, 0, 0);
    }
    __syncthreads();
  }

  if (EPI == 0) {
#pragma unroll
    for (int m = 0; m < 4; ++m) {
#pragma unroll
      for (int r = 0; r < 4; ++r) {
        const int p = m0 + wr * 64 + m * 16 + fq * 4 + r;
        if (p < cnt) {
          const size_t crow = (size_t)(base + p);
#pragma unroll
          for (int n = 0; n < 4; ++n) {
            const int col = n0 + wc * 64 + n * 16 + fr;
            if (col < Nvalid)
              Cv[crow * (size_t)ldc + col] = __float2bfloat16(fmaxf(acc[m][n][r], 0.f));
          }
        }
      }
    }
  } else {
    __shared__ float ssred[128][2];
#pragma unroll
    for (int m = 0; m < 4; ++m) {
#pragma unroll
      for (int r = 0; r < 4; ++r) {
        const int lr = wr * 64 + m * 16 + fq * 4 + r;
        const int p = m0 + lr;
        float rowss = 0.f;
        if (p < cnt) {
          const size_t crow = (size_t)(base + p);
#pragma unroll
          for (int n = 0; n < 4; ++n) {
            const int col = n0 + wc * 64 + n * 16 + fr;
            const float g = 0.2f * fmaxf(acc[m][n][r], 0.f) +
                            0.8f * b2f(*(const unsigned short*)&xb[crow * 1024 + col]);
            Cv[crow * (size_t)ldc + col] = __float2bfloat16(g);
            rowss += g * g;
          }
        }
        rowss += __shfl_xor(rowss, 1, 16);
        rowss += __shfl_xor(rowss, 2, 16);
        rowss += __shfl_xor(rowss, 4, 16);
        rowss += __shfl_xor(rowss, 8, 16);
        if (fr == 0) ssred[lr][wc] = rowss;
      }
    }
    __syncthreads();
    if (tid < 128) {
      const int p = m0 + tid;
      if (p < cnt)
        ssp[(size_t)nblkidx * 16384 + base + p] = ssred[tid][0] + ssred[tid][1];
    }
  }
}

// ====== GEMM3: counted-vmcnt schedule at 2 blocks/CU (R13/R16 winner — final) ======
__global__ __launch_bounds__(256, 2) void gemm3_cnt(
    const bf16* __restrict__ A, const bf16* __restrict__ BT,
    float* __restrict__ C, const float* __restrict__ scale_ptr,
    const float* __restrict__ ssp, const int* __restrict__ perm) {
  extern __shared__ bf16 smem[];
  bf16* sA0 = smem;            // [2][128][64] = 32KB
  bf16* sB0 = smem + 16384;    // [2][192][64] = 48KB

  const int tid = threadIdx.x;
  const int lane = tid & 63, wid = tid >> 6;
  const int wr = wid >> 1, wc = wid & 1;     // 2x2; wave C = 64x96
  const int fr = lane & 15, fq = lane >> 4;

  const int bid = blockIdx.x;
  const int x = bid & 7, seq = bid >> 3;
  const int mb = x * 16 + (seq >> 3), nb = seq & 7;
  const int m0 = mb << 7, n0 = nb * 192;

  auto STAGE = [&](int t) {     // A 4 + B 6 gload/thread = 10 VMEM ops/thread/tile
    const int s = t & 1, koff = t << 6;
    bf16* da = sA0 + (s << 13);
#pragma unroll
    for (int L = 0; L < 4; ++L) {
      const int idx = (L << 8) + tid;
      const int r = idx >> 3, c = idx & 7;
      gload_lds16(A + (size_t)(m0 + r) * 1024 + koff + ((c ^ (r & 7)) << 3),
                  da + ((idx & ~63) << 3));
    }
    bf16* db = sB0 + s * 12288;
#pragma unroll
    for (int L = 0; L < 6; ++L) {
      const int idx = (L << 8) + tid;
      const int r = idx >> 3, c = idx & 7;
      gload_lds16(BT + (size_t)(n0 + r) * 1024 + koff + ((c ^ (r & 7)) << 3),
                  db + ((idx & ~63) << 3));
    }
  };
  auto LDA = [&](int s, int kk, bf16x8* dst) {
    const bf16* base = sA0 + (s << 13);
#pragma unroll
    for (int m = 0; m < 4; ++m) {
      const int row = (wr << 6) + (m << 4) + fr;
      dst[m] = *(const bf16x8*)(base + (row << 6) + ((((kk << 2) + fq) ^ (fr & 7)) << 3));
    }
  };
  auto LDB = [&](int s, int kk, bf16x8* dst) {
    const bf16* base = sB0 + s * 12288;
#pragma unroll
    for (int n = 0; n < 6; ++n) {
      const int row = wc * 96 + (n << 4) + fr;
      dst[n] = *(const bf16x8*)(base + (row << 6) + ((((kk << 2) + fq) ^ (fr & 7)) << 3));
    }
  };

  f32x4 acc[4][6];
#pragma unroll
  for (int m = 0; m < 4; ++m)
#pragma unroll
    for (int n = 0; n < 6; ++n) acc[m][n] = (f32x4){0.f, 0.f, 0.f, 0.f};

  STAGE(0); STAGE(1);
  asm volatile("s_waitcnt vmcnt(10)" ::: "memory");
  __builtin_amdgcn_s_barrier();

  const int nt = 16;
  for (int t = 0; t < nt; ++t) {
    const int s = t & 1;
    bf16x8 a0[4], a1[4], b0[6], b1[6];
    LDA(s, 0, a0); LDB(s, 0, b0);
    LDA(s, 1, a1); LDB(s, 1, b1);
    asm volatile("s_waitcnt lgkmcnt(0)" ::: "memory");
    __builtin_amdgcn_sched_barrier(0);
    __builtin_amdgcn_s_barrier();
    __builtin_amdgcn_sched_barrier(0);
    if (t + 2 < nt) STAGE(t + 2);
    __builtin_amdgcn_s_setprio(1);
#pragma unroll
    for (int m = 0; m < 4; ++m)
#pragma unroll
      for (int n = 0; n < 6; ++n)
        acc[m][n] = __builtin_amdgcn_mfma_f32_16x16x32_bf16(a0[m], b0[n], acc[m][n], 0, 0, 0);
#pragma unroll
    for (int m = 0; m < 4; ++m)
#pragma unroll
      for (int n = 0; n < 6; ++n)
        acc[m][n] = __builtin_amdgcn_mfma_f32_16x16x32_bf16(a1[m], b1[n], acc[m][n], 0, 0, 0);
    __builtin_amdgcn_s_setprio(0);
    if (t + 2 < nt) {
      asm volatile("s_waitcnt vmcnt(10)" ::: "memory");
    } else if (t + 1 < nt) {
      asm volatile("s_waitcnt vmcnt(0)" ::: "memory");
    }
    __builtin_amdgcn_sched_barrier(0);
    __builtin_amdgcn_s_barrier();
    __builtin_amdgcn_sched_barrier(0);
  }

  float* rlds = (float*)smem;
  int*   plds = (int*)((char*)smem + 512);
  if (tid < 128) {
    float s = 0.f;
#pragma unroll
    for (int b = 0; b < 8; ++b) s += ssp[b * 16384 + m0 + tid];
    rlds[tid] = rsqrtf(s);
    plds[tid] = perm[m0 + tid];
  }
  __syncthreads();

  const float sc = expf(*scale_ptr);
#pragma unroll
  for (int m = 0; m < 4; ++m) {
    const int lrow = (wr << 6) + (m << 4) + (fq << 2);
#pragma unroll
    for (int r = 0; r < 4; ++r) {
      const float rv = sc * rlds[lrow + r];
      const size_t orow = (size_t)plds[lrow + r];
#pragma unroll
      for (int n = 0; n < 6; ++n) {
        const int gcol = n0 + wc * 96 + (n << 4) + fr;
        if (gcol < 1380) C[orow * 1380 + gcol] = acc[m][n][r] * rv;
      }
    }
  }
}

extern "C" void kernel_launch(void* const* d_in, const int* in_sizes, int n_in,
                              void* d_out, int out_size, void* d_ws, size_t ws_size,
                              hipStream_t stream) {
  (void)in_sizes; (void)n_in; (void)out_size; (void)ws_size;
  const float* x    = (const float*)d_in[0];
  const int*   lab  = (const int*)d_in[1];
  const float* W1   = (const float*)d_in[2];
  const float* W2   = (const float*)d_in[3];
  const float* text = (const float*)d_in[4];
  const float* lsc  = (const float*)d_in[5];
  float* out = (float*)d_out;

  const int B = 16384, D = 1024, R = 256, NTP = 1536;

  char* p = (char*)d_ws;
  auto carve = [&](size_t bytes) {
    char* r = p;
    p += (bytes + 255) & ~(size_t)255;
    return r;
  };
  int*   meta  = (int*)carve(64);
  int*   bhist = (int*)carve(64 * 3 * 4);
  int*   perm  = (int*)carve((size_t)B * 4);
  int*   iperm = (int*)carve((size_t)B * 4);
  float* ssp   = (float*)carve((size_t)8 * B * 4);
  bf16*  Xbc   = (bf16*)carve((size_t)B * D * 2);
  bf16*  W1T   = (bf16*)carve((size_t)3 * R * D * 2);
  bf16*  W2T   = (bf16*)carve((size_t)3 * D * R * 2);
  bf16*  Tb    = (bf16*)carve((size_t)NTP * D * 2);
  bf16*  H     = (bf16*)carve((size_t)B * R * 2);
  bf16*  Fbc   = (bf16*)carve((size_t)B * D * 2);

  hist_k<<<B / 256, 256, 0, stream>>>(lab, bhist);
  scatter2_k<<<B / 256, 256, 0, stream>>>(lab, bhist, meta, perm, iperm);

  prep_k<<<384 + 2048, 256, 0, stream>>>(x, text, W1, W2, iperm, Xbc, Tb, W1T, W2T);

  // GEMM1: H = relu(Xbc @ W1T[dom]^T), BK=64 — 768 blocks
  gemm_bt<0, 2, 64><<<768, 256, 0, stream>>>(
      Xbc, W1T, H, meta, R, D, R, R, nullptr, nullptr);
  // GEMM2: Fbc = 0.2*relu(H @ W2T^T) + 0.8*Xbc, BK=64 — 3072 blocks
  gemm_bt<1, 8, 64><<<3072, 256, 0, stream>>>(
      H, W2T, Fbc, meta, D, R, D, D, Xbc, ssp);
  // GEMM3: out[perm[row]] = exp(ls) * rinv[row] * (Fbc @ Tb^T) — counted-vmcnt, 2 blk/CU
  gemm3_cnt<<<1024, 256, 81920, stream>>>(Fbc, Tb, out, lsc, ssp, perm);
}